// Round 1
// baseline (5091.258 us; speedup 1.0000x reference)
//
#include <hip/hip_runtime.h>
#include <math.h>

#define HF 32
#define WF 128
#define HW 4096
#define C_DIM 684
#define H_DIM 256
#define A_DIM 512
#define V_DIM 415
#define PADR 42
#define PADC 144
#define T_STEPS 64
#define NSEG 16

// ---------------- workspace layout (float offsets) ----------------
constexpr int CT_OFF      = 0;                          // cnn_trans [hw][a]  4096*512
constexpr int KM_OFF      = CT_OFF + HW * A_DIM;        // merged kernel [121][512]
constexpr int APAD_OFF    = KM_OFF + 121 * A_DIM;       // padded alpha_sum [42][144]
constexpr int MASK_OFF    = APAD_OFF + PADR * PADC;     // downsampled mask [4096]
constexpr int ENERGY_OFF  = MASK_OFF + HW;              // [4096]
constexpr int AVG_OFF     = ENERGY_OFF + HW;            // [684] (pad 704)
constexpr int CTX_OFF     = AVG_OFF + 704;              // [684] (pad 704)
constexpr int HBUF0_OFF   = CTX_OFF + 704;              // h ping
constexpr int HBUF1_OFF   = HBUF0_OFF + 256;            // h pong
constexpr int MSUM_OFF    = HBUF1_OFF + 256;            // [1] (pad 16)
constexpr int WORDS_OFF   = MSUM_OFF + 16;              // 2 ints (ping-pong), pad 16
constexpr int PQ_OFF      = WORDS_OFF + 16;             // part_q   [16][512]
constexpr int PGHO_OFF    = PQ_OFF + NSEG * 512;        // part_gho [16][768]
constexpr int PGIO_OFF    = PGHO_OFF + NSEG * 768;      // part_gio [16][768]
constexpr int PSC_OFF     = PGIO_OFF + NSEG * 768;      // part_sc  [16][128]
constexpr int PGHIN0_OFF  = PSC_OFF + NSEG * 128;       // part_ghin ping [16][768]
constexpr int PGHIN1_OFF  = PGHIN0_OFF + NSEG * 768;    // part_ghin pong
constexpr int GI_OFF      = PGHIN1_OFF + NSEG * 768;    // GI table [415][768]
constexpr int SE_OFF      = GI_OFF + V_DIM * 768;       // SE table [415][128]
constexpr int WQT_OFF     = SE_OFF + V_DIM * 128;       // WqT   [256][512]
constexpr int WHHTIN_OFF  = WQT_OFF + 256 * 512;        // WhhT_in  [256][768]
constexpr int WHHTOUT_OFF = WHHTIN_OFF + 256 * 768;     // WhhT_out [256][768]
constexpr int WIHTOUT_OFF = WHHTOUT_OFF + 256 * 768;    // WihT_out [684][768]
constexpr int WCT_OFF     = WIHTOUT_OFF + 684 * 768;    // WcT [684][128]
constexpr int WST_OFF     = WCT_OFF + 684 * 128;        // WsT [256][128]
constexpr int WVT_OFF     = WST_OFF + 256 * 128;        // WvT [128][415]
constexpr int WS_END      = WVT_OFF + 128 * V_DIM;      // ~3.83M floats = 15.3 MB

__device__ __forceinline__ float sigmoidf_(float x) { return 1.f / (1.f + expf(-x)); }

// h1[j] for current step: gi from GI[word], gh from part_ghin reduce (slot t&1),
// h_prev from HBUF slot t&1.
__device__ __forceinline__ float compute_h1_row(const float* ws, int j, int word, int t,
                                                const float* bhh_in) {
  const float* gi = ws + GI_OFF + word * 768;
  const float* pg = ws + ((t & 1) ? PGHIN1_OFF : PGHIN0_OFF);
  float gh0 = bhh_in[j], gh1 = bhh_in[256 + j], gh2 = bhh_in[512 + j];
#pragma unroll
  for (int s = 0; s < NSEG; s++) {
    gh0 += pg[s * 768 + j];
    gh1 += pg[s * 768 + 256 + j];
    gh2 += pg[s * 768 + 512 + j];
  }
  float r = sigmoidf_(gi[j] + gh0);
  float z = sigmoidf_(gi[256 + j] + gh1);
  float n = tanhf(gi[512 + j] + r * gh2);
  float hp = ws[((t & 1) ? HBUF1_OFF : HBUF0_OFF) + j];
  return (1.f - z) * n + z * hp;
}

// ---------------- precompute kernels ----------------

__global__ void k_init(const float* __restrict__ imask, float* ws) {
  __shared__ float red[4];
  int tid = threadIdx.x;
  float s = 0.f;
  for (int i = tid; i < HW; i += 256) {
    int h = i >> 7, w = i & 127;
    float m = imask[h * 16 * 2048 + w * 16];
    ws[MASK_OFF + i] = m;
    s += m;
  }
  for (int i = tid; i < PADR * PADC; i += 256) ws[APAD_OFF + i] = 0.f;
#pragma unroll
  for (int off = 32; off; off >>= 1) s += __shfl_xor(s, off, 64);
  if ((tid & 63) == 0) red[tid >> 6] = s;
  __syncthreads();
  if (tid == 0) {
    ws[MSUM_OFF] = red[0] + red[1] + red[2] + red[3];
    ((int*)ws)[WORDS_OFF] = 1;  // emb0 = emb_table[1]
  }
}

__global__ void k_avg(const float* __restrict__ cnn, float* ws) {
  __shared__ float red[4];
  int c = blockIdx.x, tid = threadIdx.x;
  const float* row = cnn + c * HW;
  float s = 0.f;
  for (int i = tid; i < HW; i += 256) s += ws[MASK_OFF + i] * row[i];
#pragma unroll
  for (int off = 32; off; off >>= 1) s += __shfl_xor(s, off, 64);
  if ((tid & 63) == 0) red[tid >> 6] = s;
  __syncthreads();
  if (tid == 0) ws[AVG_OFF + c] = (red[0] + red[1] + red[2] + red[3]) / ws[MSUM_OFF];
}

__global__ void k_h0(const float* __restrict__ W_init, const float* __restrict__ b_init, float* ws) {
  __shared__ float a_s[C_DIM];
  int tid = threadIdx.x;
  for (int i = tid; i < C_DIM; i += 256) a_s[i] = ws[AVG_OFF + i];
  __syncthreads();
  const float* wr = W_init + tid * C_DIM;
  float s = b_init[tid];
  for (int k = 0; k < C_DIM; k++) s += a_s[k] * wr[k];
  ws[HBUF0_OFF + tid] = tanhf(s);
}

__global__ __launch_bounds__(512) void k_km(const float* __restrict__ convk,
                                            const float* __restrict__ Wcov, float* ws) {
  __shared__ float kt[256];
  int t = blockIdx.x, a = threadIdx.x;
  if (a < 256) kt[a] = convk[a * 121 + t];
  __syncthreads();
  const float* wr = Wcov + a * 256;
  float s = 0.f;
  for (int c = 0; c < 256; c++) s += kt[c] * wr[c];
  ws[KM_OFF + t * A_DIM + a] = s;
}

// cnn_trans GEMM: ct[hw][a] = sum_c cnn[c][hw]*Wproj[a][c] + bproj[a]
// BM=128 (hw), BN=64 (a), BK=8; block 256 threads, 8x4 microtile.
__global__ void k_ct(const float* __restrict__ cnn, const float* __restrict__ Wproj,
                     const float* __restrict__ bproj, float* ws) {
  __shared__ float As[8][128];
  __shared__ float Bs[8][64];
  int hw0 = blockIdx.x * 128;
  int a0 = blockIdx.y * 64;
  int tid = threadIdx.x;
  int tx = tid & 15, ty = tid >> 4;
  float acc[8][4];
#pragma unroll
  for (int i = 0; i < 8; i++)
#pragma unroll
    for (int j = 0; j < 4; j++) acc[i][j] = 0.f;

  for (int c0 = 0; c0 < C_DIM; c0 += 8) {
    {
      int kk = tid >> 5;
      int m4 = (tid & 31) * 4;
      int c = c0 + kk;
      float4 v = make_float4(0.f, 0.f, 0.f, 0.f);
      if (c < C_DIM) v = *(const float4*)(cnn + c * HW + hw0 + m4);
      *(float4*)&As[kk][m4] = v;
    }
    {
      int n = tid & 63;
      int kk0 = (tid >> 6) * 2;
      const float* wr = Wproj + (a0 + n) * C_DIM + c0;
      Bs[kk0][n]     = (c0 + kk0 < C_DIM) ? wr[kk0] : 0.f;
      Bs[kk0 + 1][n] = (c0 + kk0 + 1 < C_DIM) ? wr[kk0 + 1] : 0.f;
    }
    __syncthreads();
#pragma unroll
    for (int kk = 0; kk < 8; kk++) {
      float a8[8], b4[4];
#pragma unroll
      for (int i = 0; i < 8; i++) a8[i] = As[kk][ty * 8 + i];
#pragma unroll
      for (int j = 0; j < 4; j++) b4[j] = Bs[kk][tx * 4 + j];
#pragma unroll
      for (int i = 0; i < 8; i++)
#pragma unroll
        for (int j = 0; j < 4; j++) acc[i][j] += a8[i] * b4[j];
    }
    __syncthreads();
  }
#pragma unroll
  for (int i = 0; i < 8; i++) {
    int hw = hw0 + ty * 8 + i;
#pragma unroll
    for (int j = 0; j < 4; j++) {
      int a = a0 + tx * 4 + j;
      ws[CT_OFF + hw * A_DIM + a] = acc[i][j] + bproj[a];
    }
  }
}

__global__ void k_gi(const float* __restrict__ emb_table, const float* __restrict__ Wih_in,
                     const float* __restrict__ bih_in, float* ws) {
  __shared__ float e_s[256];
  int v = blockIdx.x, tid = threadIdx.x;
  e_s[tid] = emb_table[v * 256 + tid];
  __syncthreads();
#pragma unroll
  for (int r = 0; r < 3; r++) {
    int m = r * 256 + tid;
    const float* wr = Wih_in + m * 256;
    float s = bih_in[m];
    for (int k = 0; k < 256; k++) s += e_s[k] * wr[k];
    ws[GI_OFF + v * 768 + m] = s;
  }
}

__global__ void k_se(const float* __restrict__ emb_table, const float* __restrict__ We,
                     const float* __restrict__ be, float* ws) {
  __shared__ float e_s[256];
  int v = blockIdx.x, tid = threadIdx.x;  // 128 threads
  e_s[tid] = emb_table[v * 256 + tid];
  e_s[tid + 128] = emb_table[v * 256 + tid + 128];
  __syncthreads();
  const float* wr = We + tid * 256;
  float s = be[tid];
  for (int k = 0; k < 256; k++) s += e_s[k] * wr[k];
  ws[SE_OFF + v * 128 + tid] = s;
}

// generic transpose: in (M x Kd) -> out (Kd x M)
__global__ void k_tr(const float* __restrict__ in, float* __restrict__ out, int M, int Kd) {
  int total = M * Kd;
  for (int i = blockIdx.x * blockDim.x + threadIdx.x; i < total; i += gridDim.x * blockDim.x) {
    int m = i / Kd, k = i - m * Kd;
    out[k * M + m] = in[i];
  }
}

// part_ghin (slot 0) from h0
__global__ void k_ghin0(float* ws) {
  __shared__ float hk[16];
  int b = blockIdx.x, tid = threadIdx.x;
  if (tid < 16) hk[tid] = ws[HBUF0_OFF + b * 16 + tid];
  __syncthreads();
  const float* wt = ws + WHHTIN_OFF;
#pragma unroll
  for (int r = 0; r < 3; r++) {
    int m = r * 256 + tid;
    float s = 0.f;
#pragma unroll
    for (int kk = 0; kk < 16; kk++) s += hk[kk] * wt[(b * 16 + kk) * 768 + m];
    ws[PGHIN0_OFF + b * 768 + m] = s;
  }
}

// ---------------- per-step kernels ----------------

// KA: redundant h1 per block; write part_q (WqT) and part_gho (WhhT_out). 16 blocks x 256.
__global__ void k_pre(const float* __restrict__ bhh_in, float* ws, int t) {
  __shared__ float h1_s[256];
  int tid = threadIdx.x, b = blockIdx.x;
  int word = ((const int*)ws)[WORDS_OFF + (t & 1)];
  h1_s[tid] = compute_h1_row(ws, tid, word, t, bhh_in);
  __syncthreads();
  int k0 = b * 16;
  float hk[16];
#pragma unroll
  for (int kk = 0; kk < 16; kk++) hk[kk] = h1_s[k0 + kk];
  const float* wqt = ws + WQT_OFF;
  const float* wht = ws + WHHTOUT_OFF;
#pragma unroll
  for (int r = 0; r < 2; r++) {
    int a = r * 256 + tid;
    float s = 0.f;
#pragma unroll
    for (int kk = 0; kk < 16; kk++) s += hk[kk] * wqt[(k0 + kk) * 512 + a];
    ws[PQ_OFF + b * 512 + a] = s;
  }
#pragma unroll
  for (int r = 0; r < 3; r++) {
    int m = r * 256 + tid;
    float s = 0.f;
#pragma unroll
    for (int kk = 0; kk < 16; kk++) s += hk[kk] * wht[(k0 + kk) * 768 + m];
    ws[PGHO_OFF + b * 768 + m] = s;
  }
}

// KB: energy. 256 blocks (16 hw each) x 512 threads (one per a).
__global__ __launch_bounds__(512) void k_energy(const float* __restrict__ wa,
                                                const float* __restrict__ ba,
                                                const float* __restrict__ bq, float* ws) {
  int b = blockIdx.x;
  int h = b >> 3, w0 = (b & 7) * 16;
  int a = threadIdx.x;
  __shared__ float patch[11][32];
  __shared__ float red[8][16];
  for (int i = a; i < 11 * 26; i += 512) {
    int r = i / 26, c = i - r * 26;
    patch[r][c] = ws[APAD_OFF + (h + r) * PADC + w0 + c];
  }
  __syncthreads();
  float acc[16];
#pragma unroll
  for (int i = 0; i < 16; i++) acc[i] = 0.f;
  const float* km = ws + KM_OFF;
  for (int dy = 0; dy < 11; dy++) {
    float row[26];
#pragma unroll
    for (int i = 0; i < 26; i++) row[i] = patch[dy][i];
    float kv[11];
#pragma unroll
    for (int dx = 0; dx < 11; dx++) kv[dx] = km[(dy * 11 + dx) * A_DIM + a];
#pragma unroll
    for (int dx = 0; dx < 11; dx++)
#pragma unroll
      for (int wi = 0; wi < 16; wi++) acc[wi] += kv[dx] * row[wi + dx];
  }
  float qa = bq[a];
#pragma unroll
  for (int s = 0; s < NSEG; s++) qa += ws[PQ_OFF + s * 512 + a];
  float waa = wa[a];
  int hw0 = h * WF + w0;
  const float* ct = ws + CT_OFF;
  float part[16];
#pragma unroll
  for (int wi = 0; wi < 16; wi++) {
    float x = acc[wi] + qa + ct[(hw0 + wi) * A_DIM + a];
    part[wi] = tanhf(x) * waa;
  }
  int lane = a & 63, wv = a >> 6;
#pragma unroll
  for (int wi = 0; wi < 16; wi++) {
    float v2 = part[wi];
#pragma unroll
    for (int off = 32; off; off >>= 1) v2 += __shfl_xor(v2, off, 64);
    if (lane == 0) red[wv][wi] = v2;
  }
  __syncthreads();
  if (a < 16) {
    float e = ba[0];
#pragma unroll
    for (int w2 = 0; w2 < 8; w2++) e += red[w2][a];
    int hw = hw0 + a;
    ws[ENERGY_OFF + hw] = (ws[MASK_OFF + hw] > 0.f) ? e : -1e9f;
  }
}

// KC: softmax (redundant per block) + ctx (4 channels/block); block 0 also updates alpha_pad.
__global__ void k_softctx(const float* __restrict__ cnn, float* ws) {
  __shared__ float alpha_s[HW];
  __shared__ float red[4];
  int tid = threadIdx.x;
  const float* energy = ws + ENERGY_OFF;
  float ev[16];
  float mx = -3.4e38f;
#pragma unroll
  for (int i = 0; i < 16; i++) {
    ev[i] = energy[tid + i * 256];
    mx = fmaxf(mx, ev[i]);
  }
#pragma unroll
  for (int off = 32; off; off >>= 1) mx = fmaxf(mx, __shfl_xor(mx, off, 64));
  if ((tid & 63) == 0) red[tid >> 6] = mx;
  __syncthreads();
  mx = fmaxf(fmaxf(red[0], red[1]), fmaxf(red[2], red[3]));
  __syncthreads();
  float s = 0.f;
#pragma unroll
  for (int i = 0; i < 16; i++) {
    ev[i] = expf(ev[i] - mx);
    s += ev[i];
  }
#pragma unroll
  for (int off = 32; off; off >>= 1) s += __shfl_xor(s, off, 64);
  if ((tid & 63) == 0) red[tid >> 6] = s;
  __syncthreads();
  float S = red[0] + red[1] + red[2] + red[3];
  float inv = 1.f / S;
#pragma unroll
  for (int i = 0; i < 16; i++) alpha_s[tid + i * 256] = ev[i] * inv;
  __syncthreads();
  if (blockIdx.x == 0) {
    for (int i = tid; i < HW; i += 256) {
      int hh = i >> 7, ww = i & 127;
      ws[APAD_OFF + (hh + 5) * PADC + ww + 5] += alpha_s[i];
    }
  }
  int c0 = blockIdx.x * 4;
  for (int cc = 0; cc < 4; cc++) {
    int c = c0 + cc;
    const float* row = cnn + c * HW;
    float p = 0.f;
    for (int i = tid; i < HW; i += 256) p += alpha_s[i] * row[i];
#pragma unroll
    for (int off = 32; off; off >>= 1) p += __shfl_xor(p, off, 64);
    __syncthreads();
    if ((tid & 63) == 0) red[tid >> 6] = p;
    __syncthreads();
    if (tid == 0) ws[CTX_OFF + c] = red[0] + red[1] + red[2] + red[3];
  }
}

// KD: part_gio (WihT_out . ctx) and part_sc (WcT . ctx). 16 blocks x 256, k-seg 43.
__global__ void k_gio(float* ws) {
  __shared__ float ctx_s[43];
  int tid = threadIdx.x, b = blockIdx.x;
  int k0 = b * 43;
  if (tid < 43) ctx_s[tid] = (k0 + tid < C_DIM) ? ws[CTX_OFF + k0 + tid] : 0.f;
  __syncthreads();
  const float* wt = ws + WIHTOUT_OFF;
#pragma unroll
  for (int r = 0; r < 3; r++) {
    int m = r * 256 + tid;
    float s = 0.f;
    for (int kk = 0; kk < 43; kk++) {
      int k = k0 + kk;
      int kc = (k < C_DIM) ? k : (C_DIM - 1);
      s += ctx_s[kk] * wt[kc * 768 + m];
    }
    ws[PGIO_OFF + b * 768 + m] = s;
  }
  if (tid < 128) {
    const float* wct = ws + WCT_OFF;
    float s = 0.f;
    for (int kk = 0; kk < 43; kk++) {
      int k = k0 + kk;
      int kc = (k < C_DIM) ? k : (C_DIM - 1);
      s += ctx_s[kk] * wct[kc * 128 + tid];
    }
    ws[PSC_OFF + b * 128 + tid] = s;
  }
}

// KE: 17 blocks x 768. All blocks: reduce gio/gho + h1 -> h (redundant).
// Block 0: state, prob, argmax, out row, next word. Blocks 1..16: part_ghin for next step.
__global__ __launch_bounds__(768) void k_fin(const float* __restrict__ bih_out,
                                             const float* __restrict__ bhh_out,
                                             const float* __restrict__ bhh_in,
                                             const float* __restrict__ bs_,
                                             const float* __restrict__ bc_,
                                             const float* __restrict__ bv_,
                                             float* ws, float* __restrict__ out, int t) {
  __shared__ float gio_s[768], gho_s[768], h1_s[256], h_s[256], state_s[128];
  __shared__ float sval[768];
  __shared__ int sidx[768];
  int tid = threadIdx.x;
  int word = ((const int*)ws)[WORDS_OFF + (t & 1)];
  // p1: reduce partials
  {
    float a1 = bih_out[tid], a2 = bhh_out[tid];
#pragma unroll
    for (int s = 0; s < NSEG; s++) {
      a1 += ws[PGIO_OFF + s * 768 + tid];
      a2 += ws[PGHO_OFF + s * 768 + tid];
    }
    gio_s[tid] = a1;
    gho_s[tid] = a2;
    if (tid < 256) h1_s[tid] = compute_h1_row(ws, tid, word, t, bhh_in);
  }
  __syncthreads();
  // p2: out-GRU gates -> h
  if (tid < 256) {
    float r = sigmoidf_(gio_s[tid] + gho_s[tid]);
    float z = sigmoidf_(gio_s[256 + tid] + gho_s[256 + tid]);
    float n = tanhf(gio_s[512 + tid] + r * gho_s[512 + tid]);
    float h = (1.f - z) * n + z * h1_s[tid];
    h_s[tid] = h;
    if (blockIdx.x == 0) ws[(((t + 1) & 1) ? HBUF1_OFF : HBUF0_OFF) + tid] = h;
  }
  __syncthreads();
  if (blockIdx.x == 0) {
    // p3: state
    if (tid < 128) {
      float s = bs_[tid] + bc_[tid] + ws[SE_OFF + word * 128 + tid];
#pragma unroll
      for (int sg = 0; sg < NSEG; sg++) s += ws[PSC_OFF + sg * 128 + tid];
      const float* wst = ws + WST_OFF;
      for (int k = 0; k < 256; k++) s += h_s[k] * wst[k * 128 + tid];
      state_s[tid] = s;
    }
    __syncthreads();
    // p4: prob + argmax
    float best = -3.4e38f;
    int bi = 0;
    if (tid < V_DIM) {
      const float* wvt = ws + WVT_OFF;
      float p = bv_[tid];
      for (int k = 0; k < 128; k++) p += state_s[k] * wvt[k * V_DIM + tid];
      out[t * V_DIM + tid] = p;
      best = p;
      bi = tid;
    }
    sval[tid] = best;
    sidx[tid] = bi;
    __syncthreads();
    int m = 768;
    while (m > 3) {
      int s2 = m >> 1;
      if (tid < s2) {
        float ov = sval[tid + s2];
        int oi = sidx[tid + s2];
        if (ov > sval[tid] || (ov == sval[tid] && oi < sidx[tid])) {
          sval[tid] = ov;
          sidx[tid] = oi;
        }
      }
      __syncthreads();
      m = s2;
    }
    if (tid == 0) {
      float bv0 = sval[0];
      int bi0 = sidx[0];
      for (int i = 1; i < 3; i++) {
        if (sval[i] > bv0 || (sval[i] == bv0 && sidx[i] < bi0)) {
          bv0 = sval[i];
          bi0 = sidx[i];
        }
      }
      ((int*)ws)[WORDS_OFF + ((t + 1) & 1)] = bi0;
    }
  } else {
    // p5: part_ghin for next step (slot (t+1)&1)
    int seg = blockIdx.x - 1;
    const float* wt = ws + WHHTIN_OFF;
    float* dst = ws + (((t + 1) & 1) ? PGHIN1_OFF : PGHIN0_OFF);
    float hk[16];
#pragma unroll
    for (int kk = 0; kk < 16; kk++) hk[kk] = h_s[seg * 16 + kk];
    float s = 0.f;
#pragma unroll
    for (int kk = 0; kk < 16; kk++) s += hk[kk] * wt[(seg * 16 + kk) * 768 + tid];
    dst[seg * 768 + tid] = s;
  }
}

// ---------------- host ----------------

extern "C" void kernel_launch(void* const* d_in, const int* in_sizes, int n_in,
                              void* d_out, int out_size, void* d_ws, size_t ws_size,
                              hipStream_t stream) {
  (void)in_sizes; (void)n_in; (void)out_size; (void)ws_size;
  const float* cnn      = (const float*)d_in[0];
  const float* imask    = (const float*)d_in[1];
  const float* emb_tab  = (const float*)d_in[2];
  const float* W_init   = (const float*)d_in[3];
  const float* b_init   = (const float*)d_in[4];
  const float* Wih_in   = (const float*)d_in[5];
  const float* Whh_in   = (const float*)d_in[6];
  const float* bih_in   = (const float*)d_in[7];
  const float* bhh_in   = (const float*)d_in[8];
  const float* Wih_out  = (const float*)d_in[9];
  const float* Whh_out  = (const float*)d_in[10];
  const float* bih_out  = (const float*)d_in[11];
  const float* bhh_out  = (const float*)d_in[12];
  const float* Wq       = (const float*)d_in[13];
  const float* bq       = (const float*)d_in[14];
  const float* Wproj    = (const float*)d_in[15];
  const float* bproj    = (const float*)d_in[16];
  const float* convk    = (const float*)d_in[17];
  const float* Wcov     = (const float*)d_in[18];
  const float* wa       = (const float*)d_in[19];
  const float* ba       = (const float*)d_in[20];
  const float* Ws_      = (const float*)d_in[21];
  const float* bs_      = (const float*)d_in[22];
  const float* We_      = (const float*)d_in[23];
  const float* be_      = (const float*)d_in[24];
  const float* Wc_      = (const float*)d_in[25];
  const float* bc_      = (const float*)d_in[26];
  const float* Wv_      = (const float*)d_in[27];
  const float* bv_      = (const float*)d_in[28];
  float* ws  = (float*)d_ws;
  float* out = (float*)d_out;

  // precompute
  k_init<<<1, 256, 0, stream>>>(imask, ws);
  k_avg<<<C_DIM, 256, 0, stream>>>(cnn, ws);
  k_h0<<<1, 256, 0, stream>>>(W_init, b_init, ws);
  k_km<<<121, 512, 0, stream>>>(convk, Wcov, ws);
  k_ct<<<dim3(HW / 128, A_DIM / 64), 256, 0, stream>>>(cnn, Wproj, bproj, ws);
  k_gi<<<V_DIM, 256, 0, stream>>>(emb_tab, Wih_in, bih_in, ws);
  k_se<<<V_DIM, 128, 0, stream>>>(emb_tab, We_, be_, ws);
  k_tr<<<512, 256, 0, stream>>>(Wq, ws + WQT_OFF, 512, 256);
  k_tr<<<512, 256, 0, stream>>>(Whh_in, ws + WHHTIN_OFF, 768, 256);
  k_tr<<<512, 256, 0, stream>>>(Whh_out, ws + WHHTOUT_OFF, 768, 256);
  k_tr<<<512, 256, 0, stream>>>(Wih_out, ws + WIHTOUT_OFF, 768, 684);
  k_tr<<<512, 256, 0, stream>>>(Wc_, ws + WCT_OFF, 128, 684);
  k_tr<<<512, 256, 0, stream>>>(Ws_, ws + WST_OFF, 128, 256);
  k_tr<<<512, 256, 0, stream>>>(Wv_, ws + WVT_OFF, 415, 128);
  k_ghin0<<<16, 256, 0, stream>>>(ws);

  for (int t = 0; t < T_STEPS; t++) {
    k_pre<<<16, 256, 0, stream>>>(bhh_in, ws, t);
    k_energy<<<256, 512, 0, stream>>>(wa, ba, bq, ws);
    k_softctx<<<171, 256, 0, stream>>>(cnn, ws);
    k_gio<<<16, 256, 0, stream>>>(ws);
    k_fin<<<17, 768, 0, stream>>>(bih_out, bhh_out, bhh_in, bs_, bc_, bv_, ws, out, t);
  }
}